// Round 19
// baseline (103.095 us; speedup 1.0000x reference)
//
#include <hip/hip_runtime.h>
#include <hip/hip_bf16.h>

#define NROW 8192
#define NF   128
#define LOG2E 1.4426950408889634f

typedef float f32x4  __attribute__((ext_vector_type(4)));
typedef int   i32x4  __attribute__((ext_vector_type(4)));
typedef short bf16x8 __attribute__((ext_vector_type(8)));
typedef short bf16x4 __attribute__((ext_vector_type(4)));
typedef unsigned long long u64;

__device__ __forceinline__ short f2bf(float f) {
    union { float f; unsigned u; } v; v.f = f;
    unsigned r = v.u + 0x7FFFu + ((v.u >> 16) & 1u);
    return (short)(r >> 16);
}

__device__ __forceinline__ void gload_lds16(const short* g, short* l) {
    __builtin_amdgcn_global_load_lds(
        (const __attribute__((address_space(1))) void*)g,
        (__attribute__((address_space(3))) void*)l, 16, 0, 0);
}

// Tiled B layout (LDS-image order): element (f, j) ->
//   (j>>6)*8192 + (f>>4)*1024 + ((j>>5)&1)*512 + ((j>>3)&3)*128 + (f&15)*8 + (j&7)

// k0: WT[c][k] = bf16(W[k][c])
__global__ __launch_bounds__(256) void k0_wt(const float* __restrict__ W,
                                             short* __restrict__ WT) {
    int idx = blockIdx.x * 256 + threadIdx.x;
    int c = idx >> 7, k = idx & 127;
    WT[c * NF + k] = f2bf(W[k * NF + c]);
}

// k1: Wh = mo @ W via bf16 MFMA -> tiled WhT, s1/s2 = (Wh@a1, Wh@a2)*LOG2E.
__global__ __launch_bounds__(256) void k1_wh(const float* __restrict__ mo,
        const short* __restrict__ WT,
        const float* __restrict__ a1, const float* __restrict__ a2,
        short* __restrict__ WhT, float* __restrict__ s1g, float* __restrict__ s2g) {
    __shared__ float s_lds[2][32];
    int t = threadIdx.x;
    int w = t >> 6, l = t & 63, lg = l >> 4, lr = l & 15;
    int rows0 = blockIdx.x * 32;
    if (t < 64) s_lds[t >> 5][t & 31] = 0.0f;
    __syncthreads();

    f32x4 acc[2][2] = {};
#pragma unroll
    for (int ks = 0; ks < 4; ++ks) {
        bf16x8 a[2], b[2];
#pragma unroll
        for (int rt = 0; rt < 2; ++rt) {
            const float* ap = mo + (size_t)(rows0 + rt*16 + lr) * NF + ks*32 + lg*8;
            f32x4 x0 = *(const f32x4*)ap;
            f32x4 x1 = *(const f32x4*)(ap + 4);
#pragma unroll
            for (int e = 0; e < 4; ++e) { a[rt][e] = f2bf(x0[e]); a[rt][4+e] = f2bf(x1[e]); }
        }
#pragma unroll
        for (int ct = 0; ct < 2; ++ct) {
            int c = w*32 + ct*16 + lr;
            b[ct] = *(const bf16x8*)(WT + c*NF + ks*32 + lg*8);
        }
#pragma unroll
        for (int rt = 0; rt < 2; ++rt)
#pragma unroll
            for (int ct = 0; ct < 2; ++ct)
                acc[rt][ct] = __builtin_amdgcn_mfma_f32_16x16x32_bf16(a[rt], b[ct], acc[rt][ct], 0, 0, 0);
    }

    // C/D layout: col = lane&15, row = (lane>>4)*4 + reg
#pragma unroll
    for (int rt = 0; rt < 2; ++rt) {
        float p1[4] = {0,0,0,0}, p2[4] = {0,0,0,0};
#pragma unroll
        for (int ct = 0; ct < 2; ++ct) {
            int c = w*32 + ct*16 + lr;
            float a1c = a1[c], a2c = a2[c];
            bf16x4 wv;
#pragma unroll
            for (int g = 0; g < 4; ++g) {
                float v = acc[rt][ct][g];
                wv[g] = f2bf(v);
                p1[g] += v * a1c;
                p2[g] += v * a2c;
            }
            int r0 = rows0 + rt*16 + lg*4;   // multiple of 4
            size_t off = (size_t)(r0 >> 6) * 8192 + (size_t)(c >> 4) * 1024
                       + (size_t)((r0 >> 5) & 1) * 512 + (size_t)((r0 >> 3) & 3) * 128
                       + (size_t)(c & 15) * 8 + (size_t)(r0 & 7);
            *(bf16x4*)(WhT + off) = wv;
        }
#pragma unroll
        for (int off = 1; off < 16; off <<= 1) {
#pragma unroll
            for (int g = 0; g < 4; ++g) {
                p1[g] += __shfl_xor(p1[g], off);
                p2[g] += __shfl_xor(p2[g], off);
            }
        }
        if (lr == 0) {
            int rloc = rt*16 + lg*4;
#pragma unroll
            for (int g = 0; g < 4; ++g) {
                atomicAdd(&s_lds[0][rloc+g], p1[g]);
                atomicAdd(&s_lds[1][rloc+g], p2[g]);
            }
        }
    }
    __syncthreads();
    if (t < 32)       s1g[rows0 + t]        = s_lds[0][t] * LOG2E;
    else if (t < 64)  s2g[rows0 + (t - 32)] = s_lds[1][t - 32] * LOG2E;
}

// k2: depth-2 adj pipeline with RAW barriers + counted vmcnt.
// In-order vmem queue per sub-iteration: [An(prev)=16][stage=8][An(next)=16].
// Top: issue stage(it+1)->Bl[cur^1] then An(it+2)->{A0|A1}. Compute tile it
// (mask ballot'd LAST iteration; no vmem consumers). vmcnt(24) -> drains only
// An(it+1); ballot it. vmcnt(16) -> drains only stage. RAW s_barrier (no
// vmcnt(0) drain!). Every wave keeps >=16 adj loads in flight at all times ->
// HBM delivery-rate-limited (fixes the 57% duty cycle of __syncthreads drain).
__global__ __launch_bounds__(256, 4) void k2_main(
        const int* __restrict__ adj, const short* __restrict__ WhT,
        const float* __restrict__ s1g, const float* __restrict__ s2g,
        float* __restrict__ numP, float* __restrict__ zP,
        int S, int npb) {
    __shared__ __attribute__((aligned(16))) short Bl[2][8192];  // 2 x 16KB
    __shared__ __attribute__((aligned(16))) float s2l[1024];    // npb <= 1024

    int t = threadIdx.x, w = t >> 6, l = t & 63;
    int lo = l & 15, hi = l >> 4;
    int b = blockIdx.x, jseg = b % S, rg = b / S;
    int wrows0 = (rg << 6) + (w << 4);
    int j0 = jseg * npb;
    int NT = npb >> 6;                          // 16 (npb=1024), even

    for (int i = t; i < (npb >> 2); i += 256)
        ((f32x4*)s2l)[i] = ((const f32x4*)(s2g + j0))[i];

    float s1v = s1g[wrows0 + lo];
    const int* arow = adj + (size_t)wrows0 * NROW + j0 + l;
    const short* wbase = WhT + (size_t)(j0 >> 6) * 8192 + w*2048 + l*8;

    f32x4 acc[8] = {};
    float z = 0.0f;

#define STAGE(BUF_, TI_) do { \
    const short* gs_ = wbase + (size_t)(TI_) * 8192; \
    short* ds_ = &Bl[BUF_][w*2048]; \
_Pragma("unroll") \
    for (int r4 = 0; r4 < 4; ++r4) gload_lds16(gs_ + r4*512, ds_ + r4*512); \
} while (0)

#define BALLOT(AR_, BQ_) do { \
    u64 m_ = 0; \
_Pragma("unroll") \
    for (int r = 0; r < 16; ++r) { \
        u64 br_ = __ballot(AR_[r] > 0); \
        m_ = (lo == r) ? br_ : m_; \
    } \
    BQ_ = m_; \
} while (0)

#define REFILL(AR_, TI_) do { \
    int jo_ = (TI_) << 6; \
_Pragma("unroll") \
    for (int r = 0; r < 16; ++r) \
        AR_[r] = __builtin_nontemporal_load(arow + r * NROW + jo_); \
} while (0)

#define COMPUTE(IT_, BQ_, BUF_) do { \
_Pragma("unroll") \
    for (int ks = 0; ks < 2; ++ks) { \
        unsigned bits_ = (unsigned)((BQ_) >> ((ks << 5) + hi * 8)) & 0xffu; \
        int js_ = ((IT_) << 6) + ks * 32 + hi * 8; \
        f32x4 sa_ = *(const f32x4*)(s2l + js_); \
        f32x4 sb_ = *(const f32x4*)(s2l + js_ + 4); \
        float p_[8]; \
_Pragma("unroll") \
        for (int e = 0; e < 4; ++e) { \
            float x_, pe_; \
            x_ = s1v + sa_[e]; pe_ = exp2f(fmaxf(x_, 0.2f * x_)); \
            p_[e]     = ((bits_ >> e) & 1) ? pe_ : 0.0f;        z += p_[e]; \
            x_ = s1v + sb_[e]; pe_ = exp2f(fmaxf(x_, 0.2f * x_)); \
            p_[4 + e] = ((bits_ >> (4 + e)) & 1) ? pe_ : 0.0f;  z += p_[4 + e]; \
        } \
        union { bf16x8 v8; __hip_bfloat162 h2[4]; } fau_; \
_Pragma("unroll") \
        for (int q = 0; q < 4; ++q) \
            fau_.h2[q] = __float22bfloat162_rn(make_float2(p_[2*q], p_[2*q + 1])); \
        const short* Bc_ = &Bl[BUF_][ks * 512 + l * 8]; \
_Pragma("unroll") \
        for (int ct = 0; ct < 8; ++ct) { \
            bf16x8 bv_ = *(const bf16x8*)(Bc_ + ct * 1024); \
            acc[ct] = __builtin_amdgcn_mfma_f32_16x16x32_bf16(fau_.v8, bv_, acc[ct], 0, 0, 0); \
        } \
    } \
} while (0)

    int A0[16], A1[16];
    u64 bmq0, bmq1;

    // ---- prologue: queue = [A0:16][stage0:8][A1:16] ----
    REFILL(A0, 0);
    STAGE(0, 0);
    REFILL(A1, 1);                 // NT >= 2
    asm volatile("s_waitcnt vmcnt(24)" ::: "memory");   // A0 arrived
    __builtin_amdgcn_sched_barrier(0);
    BALLOT(A0, bmq0);
    asm volatile("s_waitcnt vmcnt(16) lgkmcnt(0)" ::: "memory"); // stage0 + s2l writes done
    __builtin_amdgcn_sched_barrier(0);
    __builtin_amdgcn_s_barrier();
    __builtin_amdgcn_sched_barrier(0);

    int cur = 0;
    for (int it = 0; it < NT; it += 2) {
        // ---- even sub-iter: compute tile it with bmq0; refill A0<-it+2 ----
        {
            int t1 = (it + 1 < NT) ? it + 1 : NT - 1;
            int t2 = (it + 2 < NT) ? it + 2 : NT - 1;
            STAGE(cur ^ 1, t1);
            REFILL(A0, t2);
            COMPUTE(it, bmq0, cur);
            asm volatile("s_waitcnt vmcnt(24)" ::: "memory");   // A1 arrived
            __builtin_amdgcn_sched_barrier(0);
            BALLOT(A1, bmq1);
            asm volatile("s_waitcnt vmcnt(16)" ::: "memory");   // stage done
            __builtin_amdgcn_sched_barrier(0);
            __builtin_amdgcn_s_barrier();
            __builtin_amdgcn_sched_barrier(0);
            cur ^= 1;
        }
        // ---- odd sub-iter: compute tile it+1 with bmq1; refill A1<-it+3 ----
        {
            int t2 = (it + 2 < NT) ? it + 2 : NT - 1;
            int t3 = (it + 3 < NT) ? it + 3 : NT - 1;
            STAGE(cur ^ 1, t2);
            REFILL(A1, t3);
            COMPUTE(it + 1, bmq1, cur);
            asm volatile("s_waitcnt vmcnt(24)" ::: "memory");   // A0 arrived
            __builtin_amdgcn_sched_barrier(0);
            BALLOT(A0, bmq0);
            asm volatile("s_waitcnt vmcnt(16)" ::: "memory");   // stage done
            __builtin_amdgcn_sched_barrier(0);
            __builtin_amdgcn_s_barrier();
            __builtin_amdgcn_sched_barrier(0);
            cur ^= 1;
        }
    }
#undef STAGE
#undef BALLOT
#undef REFILL
#undef COMPUTE

    // --- epilogue: disjoint rows per wave -> direct stores, no reduction ---
    z += __shfl_xor(z, 16);
    z += __shfl_xor(z, 32);
    if (l < 16) zP[(size_t)jseg * NROW + wrows0 + lo] = z;

    size_t obase = (size_t)jseg * NROW * NF;
#pragma unroll
    for (int ct = 0; ct < 8; ++ct) {
        int cc = ct * 16 + lo;
        int r0 = wrows0 + hi * 4;
#pragma unroll
        for (int g = 0; g < 4; ++g)
            numP[obase + (size_t)(r0 + g) * NF + cc] = acc[ct][g];
    }
}

// k3: out = elu( sum_s num / sum_s z ), vectorized x4
__global__ __launch_bounds__(256) void k3_reduce(const float* __restrict__ numP,
        const float* __restrict__ zP, float* __restrict__ out, int S) {
    int idx = (blockIdx.x * 256 + threadIdx.x) * 4;
    int r = idx >> 7;
    f32x4 num = {};
    float zz = 0.0f;
    for (int s = 0; s < S; ++s) {
        f32x4 v = *(const f32x4*)(numP + (size_t)s * (NROW * NF) + idx);
        num += v;
        zz  += zP[s * NROW + r];
    }
    f32x4 o;
#pragma unroll
    for (int e = 0; e < 4; ++e) {
        float h = num[e] / zz;
        o[e] = (h > 0.0f) ? h : expm1f(h);
    }
    *(f32x4*)(out + idx) = o;
}

extern "C" void kernel_launch(void* const* d_in, const int* in_sizes, int n_in,
                              void* d_out, int out_size, void* d_ws, size_t ws_size,
                              hipStream_t stream) {
    const float* mo  = (const float*)d_in[0];
    const int*   adj = (const int*)d_in[1];
    const float* W   = (const float*)d_in[2];
    const float* a1  = (const float*)d_in[3];
    const float* a2  = (const float*)d_in[4];
    float* out = (float*)d_out;

    char* p = (char*)d_ws;
    short* WT  = (short*)p;  p += (size_t)NF * NF * 2;
    short* WhT = (short*)p;  p += (size_t)NF * NROW * 2;
    float* s1  = (float*)p;  p += (size_t)NROW * 4;
    float* s2  = (float*)p;  p += (size_t)NROW * 4;
    float* zP  = (float*)p;  p += (size_t)8 * NROW * 4;   // S<=8
    size_t fixed = (size_t)(p - (char*)d_ws);

    int S = 8;   // 128 rowgroups x 8 jsegs = 1024 blocks = 4/CU, npb=1024
    while (S > 1 && fixed + (size_t)S * NROW * NF * 4 > ws_size) S >>= 1;
    float* numP = (float*)p;
    if (fixed + (size_t)S * NROW * NF * 4 > ws_size) numP = out;  // S==1 fallback

    k0_wt<<<dim3(64), dim3(256), 0, stream>>>(W, WT);
    k1_wh<<<dim3(256), dim3(256), 0, stream>>>(mo, WT, a1, a2, WhT, s1, s2);
    k2_main<<<dim3((NROW / 64) * S), dim3(256), 0, stream>>>(adj, WhT, s1, s2, numP, zP, S, NROW / S);
    k3_reduce<<<dim3(NROW * NF / 1024), dim3(256), 0, stream>>>(numP, zP, out, S);
}

// Round 20
// 90.043 us; speedup vs baseline: 1.1450x; 1.1450x over previous
//
#include <hip/hip_runtime.h>
#include <hip/hip_bf16.h>

#define NROW 8192
#define NF   128
#define LOG2E 1.4426950408889634f

typedef float f32x4  __attribute__((ext_vector_type(4)));
typedef int   i32x4  __attribute__((ext_vector_type(4)));
typedef int   i32x2  __attribute__((ext_vector_type(2)));
typedef short bf16x8 __attribute__((ext_vector_type(8)));
typedef short bf16x4 __attribute__((ext_vector_type(4)));
typedef unsigned long long u64;

__device__ __forceinline__ short f2bf(float f) {
    union { float f; unsigned u; } v; v.f = f;
    unsigned r = v.u + 0x7FFFu + ((v.u >> 16) & 1u);
    return (short)(r >> 16);
}

// j-axis permutation (within each 128-j block): k = (j&1)*64 + ((j&127)>>1).
// j is a dummy summation index; mask (ballot of i32x2 lanes), B-tile k-axis,
// and s2 are ALL stored in permuted order, so the result is unchanged while
// adj can be read as 8B/lane contiguous (512B/instruction DRAM bursts).
__device__ __forceinline__ int pjmap(int j) {
    return (j & ~127) + ((j & 1) << 6) + ((j & 127) >> 1);
}

__device__ __forceinline__ void gload_lds16(const short* g, short* l) {
    __builtin_amdgcn_global_load_lds(
        (const __attribute__((address_space(1))) void*)g,
        (__attribute__((address_space(3))) void*)l, 16, 0, 0);
}

// Tiled B layout (LDS-image order), indexed by PERMUTED k: element (f, k) ->
//   (k>>6)*8192 + (f>>4)*1024 + ((k>>5)&1)*512 + ((k>>3)&3)*128 + (f&15)*8 + (k&7)

// k0: WT[c][k] = bf16(W[k][c])
__global__ __launch_bounds__(256) void k0_wt(const float* __restrict__ W,
                                             short* __restrict__ WT) {
    int idx = blockIdx.x * 256 + threadIdx.x;
    int c = idx >> 7, k = idx & 127;
    WT[c * NF + k] = f2bf(W[k * NF + c]);
}

// k1: Wh = mo @ W via bf16 MFMA -> tiled WhT (k-permuted), s1 (linear),
//     s2 (k-permuted), both scaled by LOG2E.
__global__ __launch_bounds__(256) void k1_wh(const float* __restrict__ mo,
        const short* __restrict__ WT,
        const float* __restrict__ a1, const float* __restrict__ a2,
        short* __restrict__ WhT, float* __restrict__ s1g, float* __restrict__ s2g) {
    __shared__ float s_lds[2][32];
    int t = threadIdx.x;
    int w = t >> 6, l = t & 63, lg = l >> 4, lr = l & 15;
    int rows0 = blockIdx.x * 32;
    if (t < 64) s_lds[t >> 5][t & 31] = 0.0f;
    __syncthreads();

    f32x4 acc[2][2] = {};
#pragma unroll
    for (int ks = 0; ks < 4; ++ks) {
        bf16x8 a[2], b[2];
#pragma unroll
        for (int rt = 0; rt < 2; ++rt) {
            const float* ap = mo + (size_t)(rows0 + rt*16 + lr) * NF + ks*32 + lg*8;
            f32x4 x0 = *(const f32x4*)ap;
            f32x4 x1 = *(const f32x4*)(ap + 4);
#pragma unroll
            for (int e = 0; e < 4; ++e) { a[rt][e] = f2bf(x0[e]); a[rt][4+e] = f2bf(x1[e]); }
        }
#pragma unroll
        for (int ct = 0; ct < 2; ++ct) {
            int c = w*32 + ct*16 + lr;
            b[ct] = *(const bf16x8*)(WT + c*NF + ks*32 + lg*8);
        }
#pragma unroll
        for (int rt = 0; rt < 2; ++rt)
#pragma unroll
            for (int ct = 0; ct < 2; ++ct)
                acc[rt][ct] = __builtin_amdgcn_mfma_f32_16x16x32_bf16(a[rt], b[ct], acc[rt][ct], 0, 0, 0);
    }

    // C/D layout: col = lane&15, row = (lane>>4)*4 + reg
#pragma unroll
    for (int rt = 0; rt < 2; ++rt) {
        float p1[4] = {0,0,0,0}, p2[4] = {0,0,0,0};
#pragma unroll
        for (int ct = 0; ct < 2; ++ct) {
            int c = w*32 + ct*16 + lr;
            float a1c = a1[c], a2c = a2[c];
#pragma unroll
            for (int g = 0; g < 4; ++g) {
                float v = acc[rt][ct][g];
                p1[g] += v * a1c;
                p2[g] += v * a2c;
                int pj = pjmap(rows0 + rt*16 + lg*4 + g);
                size_t off = (size_t)(pj >> 6) * 8192 + (size_t)(c >> 4) * 1024
                           + (size_t)((pj >> 5) & 1) * 512 + (size_t)((pj >> 3) & 3) * 128
                           + (size_t)(c & 15) * 8 + (size_t)(pj & 7);
                WhT[off] = f2bf(v);
            }
        }
#pragma unroll
        for (int off = 1; off < 16; off <<= 1) {
#pragma unroll
            for (int g = 0; g < 4; ++g) {
                p1[g] += __shfl_xor(p1[g], off);
                p2[g] += __shfl_xor(p2[g], off);
            }
        }
        if (lr == 0) {
            int rloc = rt*16 + lg*4;
#pragma unroll
            for (int g = 0; g < 4; ++g) {
                atomicAdd(&s_lds[0][rloc+g], p1[g]);
                atomicAdd(&s_lds[1][rloc+g], p2[g]);
            }
        }
    }
    __syncthreads();
    if (t < 32)       s1g[rows0 + t] = s_lds[0][t] * LOG2E;
    else if (t < 64)  s2g[pjmap(rows0 + (t - 32))] = s_lds[1][t - 32] * LOG2E;
}

// k2: R13 skeleton (best measured) with PERMUTED-j adj reads:
//  - 4 waves x 16 disjoint rows, 128-j tiles (NT=8), 32KB B tile staged via
//    global_load_lds, 2 __syncthreads per iteration, ballot at loop top.
//  - adj REFILL is i32x2 per lane: 64 lanes x 8B = 512B CONTIGUOUS per
//    instruction (2x the DRAM burst length; halves page activates).
//    ballot(A.x) -> mask for permuted k 0..63; ballot(A.y) -> k 64..127.
__global__ __launch_bounds__(256, 4) void k2_main(
        const int* __restrict__ adj, const short* __restrict__ WhT,
        const float* __restrict__ s1g, const float* __restrict__ s2g,
        float* __restrict__ numP, float* __restrict__ zP,
        int S, int npb) {
    __shared__ __attribute__((aligned(16))) short Bl[16384];  // 32KB: 2 images
    __shared__ __attribute__((aligned(16))) float s2l[1024];  // npb <= 1024

    int t = threadIdx.x, w = t >> 6, l = t & 63;
    int lo = l & 15, hi = l >> 4;
    int b = blockIdx.x, jseg = b % S, rg = b / S;
    int wrows0 = (rg << 6) + (w << 4);          // this wave's 16 rows
    int j0 = jseg * npb;
    int NT = npb >> 7;                          // 128 j per iteration

    for (int i = t; i < (npb >> 2); i += 256)
        ((f32x4*)s2l)[i] = ((const f32x4*)(s2g + j0))[i];   // already permuted

    float s1v = s1g[wrows0 + lo];
    const int* arow = adj + (size_t)wrows0 * NROW + j0 + l * 2;

    f32x4 acc[8] = {};
    float z = 0.0f;

    i32x2 An[16];
#pragma unroll
    for (int r = 0; r < 16; ++r)
        An[r] = *(const i32x2*)(arow + r * NROW);
    {   // stage tile 0 (each wave stages its 8KB quarter of the 32KB tile)
        const short* gs = WhT + (size_t)(j0 >> 6) * 8192 + w*4096 + l*8;
        short* ds = &Bl[w*4096];
#pragma unroll
        for (int r8 = 0; r8 < 8; ++r8)
            gload_lds16(gs + r8*512, ds + r8*512);
    }
    __syncthreads();   // An(0) + stage(0) complete

    for (int it = 0; it < NT; ++it) {
        // --- ballot-transpose: 2 ballots/row -> masks for permuted k halves ---
        u64 bmqA = 0, bmqB = 0;
        int more = (it + 1 < NT);
#pragma unroll
        for (int r = 0; r < 16; ++r) {
            u64 brA = __ballot(An[r][0] > 0);   // k = lane      (0..63)
            u64 brB = __ballot(An[r][1] > 0);   // k = 64 + lane (64..127)
            bmqA = (lo == r) ? brA : bmqA;
            bmqB = (lo == r) ? brB : bmqB;
        }
        if (more) {   // refill An(it+1): 512B contiguous burst per row
            int joff = (it + 1) << 7;
#pragma unroll
            for (int r = 0; r < 16; ++r)
                An[r] = *(const i32x2*)(arow + r * NROW + joff);
        }
        // --- 4 K-slices of 32 permuted-k: exp/mask into A-frag, 8 MFMAs each ---
#pragma unroll
        for (int ks = 0; ks < 4; ++ks) {
            u64 bq = (ks < 2) ? bmqA : bmqB;
            unsigned bits = (unsigned)(bq >> (((ks & 1) << 5) + hi * 8)) & 0xffu;
            int js = (it << 7) + ks * 32 + hi * 8;
            f32x4 sa = *(const f32x4*)(s2l + js);
            f32x4 sb = *(const f32x4*)(s2l + js + 4);
            float p[8];
#pragma unroll
            for (int e = 0; e < 4; ++e) {
                float x, pe;
                x = s1v + sa[e]; pe = exp2f(fmaxf(x, 0.2f * x));
                p[e]     = ((bits >> e) & 1) ? pe : 0.0f;        z += p[e];
                x = s1v + sb[e]; pe = exp2f(fmaxf(x, 0.2f * x));
                p[4 + e] = ((bits >> (4 + e)) & 1) ? pe : 0.0f;  z += p[4 + e];
            }
            union { bf16x8 v8; __hip_bfloat162 h2[4]; } fau;
#pragma unroll
            for (int q = 0; q < 4; ++q)
                fau.h2[q] = __float22bfloat162_rn(make_float2(p[2*q], p[2*q + 1]));
            const short* Bc = &Bl[(ks >> 1) * 8192 + (ks & 1) * 512 + l * 8];
#pragma unroll
            for (int ct = 0; ct < 8; ++ct) {
                bf16x8 bv = *(const bf16x8*)(Bc + ct * 1024);
                acc[ct] = __builtin_amdgcn_mfma_f32_16x16x32_bf16(fau.v8, bv, acc[ct], 0, 0, 0);
            }
        }
        __syncthreads();   // all waves done reading Bl; An(it+1) arrived
        if (more) {        // stage tile it+1 into Bl
            const short* gs = WhT + (size_t)((j0 + ((it + 1) << 7)) >> 6) * 8192 + w*4096 + l*8;
            short* ds = &Bl[w*4096];
#pragma unroll
            for (int r8 = 0; r8 < 8; ++r8)
                gload_lds16(gs + r8*512, ds + r8*512);
            __syncthreads();   // stage complete
        }
    }

    // --- epilogue: disjoint rows per wave -> direct stores, no reduction ---
    z += __shfl_xor(z, 16);
    z += __shfl_xor(z, 32);
    if (l < 16) zP[(size_t)jseg * NROW + wrows0 + lo] = z;

    size_t obase = (size_t)jseg * NROW * NF;
#pragma unroll
    for (int ct = 0; ct < 8; ++ct) {
        int cc = ct * 16 + lo;
        int r0 = wrows0 + hi * 4;
#pragma unroll
        for (int g = 0; g < 4; ++g)
            numP[obase + (size_t)(r0 + g) * NF + cc] = acc[ct][g];
    }
}

// k3: out = elu( sum_s num / sum_s z ), vectorized x4
__global__ __launch_bounds__(256) void k3_reduce(const float* __restrict__ numP,
        const float* __restrict__ zP, float* __restrict__ out, int S) {
    int idx = (blockIdx.x * 256 + threadIdx.x) * 4;
    int r = idx >> 7;
    f32x4 num = {};
    float zz = 0.0f;
    for (int s = 0; s < S; ++s) {
        f32x4 v = *(const f32x4*)(numP + (size_t)s * (NROW * NF) + idx);
        num += v;
        zz  += zP[s * NROW + r];
    }
    f32x4 o;
#pragma unroll
    for (int e = 0; e < 4; ++e) {
        float h = num[e] / zz;
        o[e] = (h > 0.0f) ? h : expm1f(h);
    }
    *(f32x4*)(out + idx) = o;
}

extern "C" void kernel_launch(void* const* d_in, const int* in_sizes, int n_in,
                              void* d_out, int out_size, void* d_ws, size_t ws_size,
                              hipStream_t stream) {
    const float* mo  = (const float*)d_in[0];
    const int*   adj = (const int*)d_in[1];
    const float* W   = (const float*)d_in[2];
    const float* a1  = (const float*)d_in[3];
    const float* a2  = (const float*)d_in[4];
    float* out = (float*)d_out;

    char* p = (char*)d_ws;
    short* WT  = (short*)p;  p += (size_t)NF * NF * 2;
    short* WhT = (short*)p;  p += (size_t)NF * NROW * 2;
    float* s1  = (float*)p;  p += (size_t)NROW * 4;
    float* s2  = (float*)p;  p += (size_t)NROW * 4;
    float* zP  = (float*)p;  p += (size_t)8 * NROW * 4;   // S<=8
    size_t fixed = (size_t)(p - (char*)d_ws);

    int S = 8;   // 128 rowgroups x 8 jsegs = 1024 blocks = 4/CU, npb=1024, NT=8
    while (S > 1 && fixed + (size_t)S * NROW * NF * 4 > ws_size) S >>= 1;
    float* numP = (float*)p;
    if (fixed + (size_t)S * NROW * NF * 4 > ws_size) numP = out;  // S==1 fallback

    k0_wt<<<dim3(64), dim3(256), 0, stream>>>(W, WT);
    k1_wh<<<dim3(256), dim3(256), 0, stream>>>(mo, WT, a1, a2, WhT, s1, s2);
    k2_main<<<dim3((NROW / 64) * S), dim3(256), 0, stream>>>(adj, WhT, s1, s2, numP, zP, S, NROW / S);
    k3_reduce<<<dim3(NROW * NF / 1024), dim3(256), 0, stream>>>(numP, zP, out, S);
}